// Round 1
// baseline (30.929 us; speedup 1.0000x reference)
//
#include <hip/hip_runtime.h>
#include <math.h>

constexpr int NB = 4;     // batch
constexpr int NN = 512;   // nodes
constexpr int ND = 32;    // feature dim
constexpr int NPE = 16;   // positional dim
constexpr float INV_SQRT_D = 0.17677669529663687f; // 1/sqrt(32)
constexpr float KSHARP = 10.0f;

__global__ __launch_bounds__(256) void fpg_kernel(
    const float* __restrict__ h,
    const float* __restrict__ pe,
    const float* __restrict__ E,
    const float* __restrict__ A,
    const float* __restrict__ Wk,
    const float* __restrict__ bk,
    const float* __restrict__ Wq,
    const float* __restrict__ bq,
    const float* __restrict__ beta,
    float* __restrict__ out)
{
    const int r = blockIdx.x;        // row id in [0, B*N)
    const int b = r >> 9;            // N = 512
    const int i = r & (NN - 1);
    const int t = threadIdx.x;

    __shared__ float sKi[ND];
    __shared__ float sHi[ND];
    __shared__ float sLi[ND];
    __shared__ float sKWq[NPE];
    __shared__ float sC0;
    __shared__ float sW[NN];    // scores -> exp -> normalized W
    __shared__ float sSig[NN];
    __shared__ float sEd[NN];
    __shared__ float sRed[4];
    __shared__ float sAcc[8][ND];

    const float* pe_i = pe + (size_t)(b * NN + i) * NPE;
    const float* h_b  = h + (size_t)b * NN * ND;

    // ---- Phase A: K_i = pe_i @ Wk + bk ; stash h_i, log(h_i) ----
    if (t < ND) {
        float acc = bk[t];
        #pragma unroll
        for (int p = 0; p < NPE; ++p) acc += pe_i[p] * Wk[p * ND + t];
        sKi[t] = acc;
        float hv = h_b[i * ND + t];
        sHi[t] = hv;
        sLi[t] = logf(hv + 1e-8f);
    }
    __syncthreads();

    // ---- Phase A2: KWq[p] = dot(K_i, Wq[p,:]) ; C0 = dot(K_i, bq) ----
    if (t < NPE) {
        float acc = 0.f;
        #pragma unroll
        for (int d = 0; d < ND; ++d) acc += sKi[d] * Wq[t * ND + d];
        sKWq[t] = acc;
    } else if (t == NPE) {
        float acc = 0.f;
        #pragma unroll
        for (int d = 0; d < ND; ++d) acc += sKi[d] * bq[d];
        sC0 = acc;
    }
    __syncthreads();

    const float Ei = E[i];

    // ---- Phase B: scores (A-masked, scaled), E-diff, sigmoid ----
    #pragma unroll
    for (int jj = 0; jj < 2; ++jj) {
        const int j = t + jj * 256;
        const float* pe_j = pe + (size_t)(b * NN + j) * NPE;
        float dot = sC0;
        #pragma unroll
        for (int p = 0; p < NPE; ++p) dot += pe_j[p] * sKWq[p];
        sW[j] = A[i * NN + j] * dot * INV_SQRT_D;
        float ed = E[j] - Ei;
        sEd[j] = ed;
        sSig[j] = 1.0f / (1.0f + expf(-KSHARP * ed));
    }
    __syncthreads();

    // ---- Phase C: softmax over j (all 512 entries; A=0 entries score 0) ----
    const int lane = t & 63;
    const int wid  = t >> 6;
    float m = fmaxf(sW[t], sW[t + 256]);
    #pragma unroll
    for (int off = 32; off >= 1; off >>= 1) m = fmaxf(m, __shfl_xor(m, off, 64));
    if (lane == 0) sRed[wid] = m;
    __syncthreads();
    const float M = fmaxf(fmaxf(sRed[0], sRed[1]), fmaxf(sRed[2], sRed[3]));
    float e0 = expf(sW[t] - M);
    float e1 = expf(sW[t + 256] - M);
    float s = e0 + e1;
    #pragma unroll
    for (int off = 32; off >= 1; off >>= 1) s += __shfl_xor(s, off, 64);
    __syncthreads();                 // all reads of sRed (for M) done
    if (lane == 0) sRed[wid] = s;
    __syncthreads();
    const float S = sRed[0] + sRed[1] + sRed[2] + sRed[3];
    const float invS = 1.0f / S;
    sW[t] = e0 * invS;
    sW[t + 256] = e1 * invS;
    __syncthreads();

    // ---- Phase D: dh[d] = sum_j W_j * (Ed_j + beta_d*(L_jd - L_id)) * (sig_j*h_jd + (1-sig_j)*h_id)
    const int d = t & (ND - 1);
    const int g = t >> 5;            // 8 j-groups
    const float hi_d = sHi[d];
    const float Li_d = sLi[d];
    const float bd   = beta[d];
    float acc = 0.f;
    for (int j = g; j < NN; j += 8) {
        const float w   = sW[j];
        const float sig = sSig[j];
        const float ed  = sEd[j];
        const float hj  = h_b[j * ND + d];
        const float Lj  = logf(hj + 1e-8f);
        const float drift = w * (ed + bd * (Lj - Li_d));
        const float wh    = sig * hj + (1.0f - sig) * hi_d;
        acc += drift * wh;
    }
    sAcc[g][d] = acc;
    __syncthreads();
    if (t < ND) {
        float rsum = 0.f;
        #pragma unroll
        for (int gg = 0; gg < 8; ++gg) rsum += sAcc[gg][t];
        out[(size_t)(b * NN + i) * ND + t] = rsum;
    }
}

extern "C" void kernel_launch(void* const* d_in, const int* in_sizes, int n_in,
                              void* d_out, int out_size, void* d_ws, size_t ws_size,
                              hipStream_t stream) {
    // input order: t, h, pe, E, A, Wk, bk, Wq, bq, beta
    const float* h    = (const float*)d_in[1];
    const float* pe   = (const float*)d_in[2];
    const float* E    = (const float*)d_in[3];
    const float* A    = (const float*)d_in[4];
    const float* Wk   = (const float*)d_in[5];
    const float* bk   = (const float*)d_in[6];
    const float* Wq   = (const float*)d_in[7];
    const float* bq   = (const float*)d_in[8];
    const float* beta = (const float*)d_in[9];
    float* out = (float*)d_out;

    fpg_kernel<<<NB * NN, 256, 0, stream>>>(h, pe, E, A, Wk, bk, Wq, bq, beta, out);
}

// Round 2
// 28.323 us; speedup vs baseline: 1.0920x; 1.0920x over previous
//
#include <hip/hip_runtime.h>
#include <math.h>

constexpr int NB = 4;     // batch
constexpr int NN = 512;   // nodes
constexpr int ND = 32;    // feature dim
constexpr int NPE = 16;   // positional dim
constexpr float INV_SQRT_D = 0.17677669529663687f; // 1/sqrt(32)
constexpr float KSHARP = 10.0f;
constexpr int TI = 2;     // output rows per block
constexpr int NT = 512;   // threads per block
constexpr int NG = NT / ND; // 16 j-groups in phase D

// Pre-kernel: L = log(h + 1e-8), computed ONCE instead of per-row-block.
__global__ __launch_bounds__(256) void logh_kernel(const float* __restrict__ h,
                                                   float* __restrict__ L, int n) {
    int idx = blockIdx.x * 256 + threadIdx.x;
    if (idx < n) L[idx] = logf(h[idx] + 1e-8f);
}

__global__ __launch_bounds__(NT, 4) void fpg_kernel(
    const float* __restrict__ h,
    const float* __restrict__ pe,
    const float* __restrict__ E,
    const float* __restrict__ A,
    const float* __restrict__ Wk,
    const float* __restrict__ bk,
    const float* __restrict__ Wq,
    const float* __restrict__ bq,
    const float* __restrict__ beta,
    const float* __restrict__ Lg,
    float* __restrict__ out)
{
    const int blk = blockIdx.x;          // [0, NB*NN/TI)
    const int b   = blk >> 8;            // 256 tiles per batch
    const int i0  = (blk & 255) * TI;
    const int t   = threadIdx.x;

    __shared__ float sK[TI][ND];
    __shared__ float sKW[TI][NPE];
    __shared__ float sC0[TI];
    __shared__ float sHi[TI][ND];
    __shared__ float sLi[TI][ND];
    __shared__ float sW[TI][NN];
    __shared__ float sEd[TI][NN];
    __shared__ float sSig[TI][NN];
    __shared__ float sRedM[TI][8];
    __shared__ float sRedS[TI][8];
    __shared__ float sAcc[TI][NG][ND];

    const float* h_b  = h  + (size_t)b * NN * ND;
    const float* L_b  = Lg + (size_t)b * NN * ND;
    const float* pe_b = pe + (size_t)b * NN * NPE;

    // ---- Phase A: K rows (pe_i @ Wk + bk); stash h_i, L_i for both rows ----
    if (t < TI * ND) {
        const int r = t >> 5, d = t & 31;
        const float* pe_i = pe_b + (size_t)(i0 + r) * NPE;
        float acc = bk[d];
        #pragma unroll
        for (int p = 0; p < NPE; ++p) acc += pe_i[p] * Wk[p * ND + d];
        sK[r][d]  = acc;
        sHi[r][d] = h_b[(i0 + r) * ND + d];
        sLi[r][d] = L_b[(i0 + r) * ND + d];
    }
    __syncthreads();

    // ---- Phase A2: KW[r][p] = dot(K_r, Wq[p,:]) ; C0[r] = dot(K_r, bq) ----
    if (t < TI * NPE) {
        const int r = t >> 4, p = t & 15;
        float acc = 0.f;
        #pragma unroll
        for (int d = 0; d < ND; ++d) acc += sK[r][d] * Wq[p * ND + d];
        sKW[r][p] = acc;
    } else if (t < TI * NPE + TI) {
        const int r = t - TI * NPE;
        float acc = 0.f;
        #pragma unroll
        for (int d = 0; d < ND; ++d) acc += sK[r][d] * bq[d];
        sC0[r] = acc;
    }
    __syncthreads();

    // ---- Phase B: one j per thread — scores (A-masked), E-diff, sigmoid ----
    {
        const int j = t;
        const float4* pj = (const float4*)(pe_b + (size_t)j * NPE);
        float pv[NPE];
        *(float4*)&pv[0]  = pj[0];
        *(float4*)&pv[4]  = pj[1];
        *(float4*)&pv[8]  = pj[2];
        *(float4*)&pv[12] = pj[3];
        float dot0 = sC0[0], dot1 = sC0[1];
        #pragma unroll
        for (int p = 0; p < NPE; ++p) {
            dot0 += pv[p] * sKW[0][p];
            dot1 += pv[p] * sKW[1][p];
        }
        const float Ej = E[j];
        const float a0 = A[(size_t)(i0 + 0) * NN + j];
        const float a1 = A[(size_t)(i0 + 1) * NN + j];
        sW[0][j] = a0 * dot0 * INV_SQRT_D;
        sW[1][j] = a1 * dot1 * INV_SQRT_D;
        const float ed0 = Ej - E[i0 + 0];
        const float ed1 = Ej - E[i0 + 1];
        sEd[0][j] = ed0;
        sEd[1][j] = ed1;
        sSig[0][j] = 1.0f / (1.0f + __expf(-KSHARP * ed0));
        sSig[1][j] = 1.0f / (1.0f + __expf(-KSHARP * ed1));
    }
    __syncthreads();

    // ---- Phase C: softmax over j for both rows ----
    const int lane = t & 63, wv = t >> 6;  // 8 waves
    float m0 = sW[0][t], m1 = sW[1][t];
    #pragma unroll
    for (int off = 32; off >= 1; off >>= 1) {
        m0 = fmaxf(m0, __shfl_xor(m0, off, 64));
        m1 = fmaxf(m1, __shfl_xor(m1, off, 64));
    }
    if (lane == 0) { sRedM[0][wv] = m0; sRedM[1][wv] = m1; }
    __syncthreads();
    float M0 = sRedM[0][0], M1 = sRedM[1][0];
    #pragma unroll
    for (int w = 1; w < 8; ++w) {
        M0 = fmaxf(M0, sRedM[0][w]);
        M1 = fmaxf(M1, sRedM[1][w]);
    }
    const float e0 = __expf(sW[0][t] - M0);
    const float e1 = __expf(sW[1][t] - M1);
    float s0 = e0, s1 = e1;
    #pragma unroll
    for (int off = 32; off >= 1; off >>= 1) {
        s0 += __shfl_xor(s0, off, 64);
        s1 += __shfl_xor(s1, off, 64);
    }
    if (lane == 0) { sRedS[0][wv] = s0; sRedS[1][wv] = s1; }
    __syncthreads();
    float S0 = 0.f, S1 = 0.f;
    #pragma unroll
    for (int w = 0; w < 8; ++w) { S0 += sRedS[0][w]; S1 += sRedS[1][w]; }
    sW[0][t] = e0 * (1.0f / S0);
    sW[1][t] = e1 * (1.0f / S1);
    __syncthreads();

    // ---- Phase D: dh[r][d] = sum_j W*(ed + beta_d*(L_jd - L_id)) * fma(sig, h_jd-h_id, h_id)
    const int d = t & 31, g = t >> 5;      // 16 j-groups
    const float bd  = beta[d];
    const float hi0 = sHi[0][d], Li0 = sLi[0][d];
    const float hi1 = sHi[1][d], Li1 = sLi[1][d];
    float acc0 = 0.f, acc1 = 0.f;
    #pragma unroll 4
    for (int j = g; j < NN; j += NG) {
        const float hj = h_b[(size_t)j * ND + d];
        const float Lj = L_b[(size_t)j * ND + d];
        // row 0
        float w  = sW[0][j];
        float dr = w * fmaf(bd, Lj - Li0, sEd[0][j]);
        float wh = fmaf(sSig[0][j], hj - hi0, hi0);
        acc0 = fmaf(dr, wh, acc0);
        // row 1
        w  = sW[1][j];
        dr = w * fmaf(bd, Lj - Li1, sEd[1][j]);
        wh = fmaf(sSig[1][j], hj - hi1, hi1);
        acc1 = fmaf(dr, wh, acc1);
    }
    sAcc[0][g][d] = acc0;
    sAcc[1][g][d] = acc1;
    __syncthreads();
    if (t < TI * ND) {
        const int r = t >> 5, dd = t & 31;
        float s = 0.f;
        #pragma unroll
        for (int gg = 0; gg < NG; ++gg) s += sAcc[r][gg][dd];
        out[(size_t)(b * NN + i0 + r) * ND + dd] = s;
    }
}

extern "C" void kernel_launch(void* const* d_in, const int* in_sizes, int n_in,
                              void* d_out, int out_size, void* d_ws, size_t ws_size,
                              hipStream_t stream) {
    // input order: t, h, pe, E, A, Wk, bk, Wq, bq, beta
    const float* h    = (const float*)d_in[1];
    const float* pe   = (const float*)d_in[2];
    const float* E    = (const float*)d_in[3];
    const float* A    = (const float*)d_in[4];
    const float* Wk   = (const float*)d_in[5];
    const float* bk   = (const float*)d_in[6];
    const float* Wq   = (const float*)d_in[7];
    const float* bq   = (const float*)d_in[8];
    const float* beta = (const float*)d_in[9];
    float* out = (float*)d_out;
    float* Lg  = (float*)d_ws;   // 65536 floats = 256 KB of log(h+1e-8)

    const int n = NB * NN * ND;  // 65536
    logh_kernel<<<(n + 255) / 256, 256, 0, stream>>>(h, Lg, n);
    fpg_kernel<<<NB * NN / TI, NT, 0, stream>>>(h, pe, E, A, Wk, bk, Wq, bq, beta, Lg, out);
}